// Round 1
// baseline (63.734 us; speedup 1.0000x reference)
//
#include <hip/hip_runtime.h>
#include <math.h>
#include <limits.h>

#define LL 2048
#define PP (LL*3)
#define FPB 64

// -------- device-global scratch (rewritten every call) --------
__device__ float g_trot[LL*9];
__device__ float g_ttran[LL*3];
__device__ int   g_firstj[LL];
__device__ int   g_cnt[LL];
__device__ int   g_ii[LL];
__device__ int   g_jj[LL];
__device__ int   g_K;
__device__ float g_paug[(2*LL)*9];
__device__ float g_taug[(2*LL)*9];
__device__ float g_prot_a[(2*LL)*9];
__device__ float g_ptran_a[(2*LL)*3];
__device__ float g_trot_a[(2*LL)*9];
__device__ float g_ttran_a[(2*LL)*3];
__device__ double g_sum[2];

// rigid_from_3points for one residue: x = 9 floats (x1,x2,x3 rows)
__device__ inline void rigid3(const float* x, float* rot, float* tran) {
  float x1x=x[0],x1y=x[1],x1z=x[2];
  float x2x=x[3],x2y=x[4],x2z=x[5];
  float x3x=x[6],x3y=x[7],x3z=x[8];
  float v1x=x3x-x2x, v1y=x3y-x2y, v1z=x3z-x2z;
  float v2x=x1x-x2x, v2y=x1y-x2y, v2z=x1z-x2z;
  float n1 = sqrtf(v1x*v1x+v1y*v1y+v1z*v1z) + 0.001f;
  float e1x=v1x/n1, e1y=v1y/n1, e1z=v1z/n1;
  float dd = e1x*v2x+e1y*v2y+e1z*v2z;
  float u2x=v2x-e1x*dd, u2y=v2y-e1y*dd, u2z=v2z-e1z*dd;
  float n2 = sqrtf(u2x*u2x+u2y*u2y+u2z*u2z) + 1e-8f;
  float e2x=u2x/n2, e2y=u2y/n2, e2z=u2z/n2;
  float e3x = e1y*e2z - e1z*e2y;
  float e3y = e1z*e2x - e1x*e2z;
  float e3z = e1x*e2y - e1y*e2x;
  rot[0]=e1x; rot[1]=e1y; rot[2]=e1z;
  rot[3]=e2x; rot[4]=e2y; rot[5]=e2z;
  rot[6]=e3x; rot[7]=e3y; rot[8]=e3z;
  tran[0]=x2x; tran[1]=x2y; tran[2]=x2z;
}

__global__ void k_init() {
  int i = blockIdx.x*blockDim.x + threadIdx.x;
  if (i < LL) g_firstj[i] = INT_MAX;
  if (i == 0) { g_sum[0] = 0.0; g_sum[1] = 0.0; }
}

__global__ void k_tframes(const float* __restrict__ target) {
  int n = blockIdx.x*blockDim.x + threadIdx.x;
  if (n < LL) rigid3(target + n*9, g_trot + n*9, g_ttran + n*3);
}

// first nonzero above the diagonal per row (triu(m,1) semantics)
__global__ void k_findpairs(const int* __restrict__ m) {
  int idx = blockIdx.x*blockDim.x + threadIdx.x;
  int i = idx >> 11;      // / 2048
  int j = idx & (LL-1);   // % 2048
  if (j > i && m[idx] != 0) atomicMin(&g_firstj[i], j);
}

// single block: exclusive prefix-sum of "row has pair", build ii/jj, K
__global__ void __launch_bounds__(1024) k_scan() {
  int t = threadIdx.x;
  int r0 = 2*t, r1 = 2*t+1;
  int f0 = g_firstj[r0], f1 = g_firstj[r1];
  int h0 = (f0 != INT_MAX) ? 1 : 0;
  int h1 = (f1 != INT_MAX) ? 1 : 0;
  int local = h0 + h1;
  int lane = t & 63;
  int wid  = t >> 6;                 // 16 waves
  int incl = local;
  for (int o = 1; o < 64; o <<= 1) {
    int v = __shfl_up(incl, o);
    if (lane >= o) incl += v;
  }
  __shared__ int wsum[16];
  if (lane == 63) wsum[wid] = incl;
  __syncthreads();
  if (t < 16) {
    int iv = wsum[t];
    for (int o = 1; o < 16; o <<= 1) {
      int u = __shfl_up(iv, o);
      if (t >= o) iv += u;
    }
    wsum[t] = iv;
  }
  __syncthreads();
  int waveoff = (wid == 0) ? 0 : wsum[wid-1];
  int excl = waveoff + incl - local;   // pairs among rows < r0
  g_cnt[r0] = excl;
  g_cnt[r1] = excl + h0;
  if (h0) { g_ii[excl]      = r0; g_jj[excl]      = f0; }
  if (h1) { g_ii[excl + h0] = r1; g_jj[excl + h0] = f1; }
  if (t == 1023) g_K = waveoff + incl;
}

__global__ void k_build_aug(const float* __restrict__ coor,
                            const float* __restrict__ target) {
  int idx = blockIdx.x*blockDim.x + threadIdx.x;
  if (idx < LL) {
    int pos = idx + g_cnt[idx];
    #pragma unroll
    for (int c = 0; c < 9; ++c) {
      g_paug[pos*9+c] = coor[idx*9+c];
      g_taug[pos*9+c] = target[idx*9+c];
    }
  } else {
    int k = idx - LL;
    if (k < g_K) {
      int a = g_ii[k], b = g_jj[k];
      int pos = a + k + 1;
      #pragma unroll
      for (int c = 0; c < 9; ++c) {
        g_paug[pos*9+c] = 0.5f*(coor[a*9+c]   + coor[b*9+c]);
        g_taug[pos*9+c] = 0.5f*(target[a*9+c] + target[b*9+c]);
      }
    }
  }
}

__global__ void k_aug_frames() {
  int n = blockIdx.x*blockDim.x + threadIdx.x;
  int tot = LL + g_K;
  if (n < tot) {
    rigid3(g_paug + n*9, g_prot_a + n*9, g_ptran_a + n*3);
    rigid3(g_taug + n*9, g_trot_a + n*9, g_ttran_a + n*3);
  }
}

// fused FAPE: frame f in [0,LL) -> term0 (clamp 40); f in [LL, LL+LL+K) -> term1 (clamp 5)
__global__ void __launch_bounds__(256) k_fape(const float* __restrict__ coor,
                                              const float* __restrict__ prot,
                                              const float* __restrict__ ptran,
                                              const float* __restrict__ target) {
  __shared__ float sh[FPB*24];
  int K = g_K;
  int Ftot = 2*LL + K;
  int f0 = blockIdx.y * FPB;
  if (f0 >= Ftot) return;
  int nf = min(FPB, Ftot - f0);
  int t = threadIdx.x;

  for (int i = t; i < nf*24; i += 256) {
    int f = f0 + i/24;
    int c = i % 24;
    float v;
    if (f < LL) {
      if      (c < 9)  v = prot[f*9 + c];
      else if (c < 12) v = ptran[f*3 + c-9];
      else if (c < 21) v = g_trot[f*9 + c-12];
      else             v = g_ttran[f*3 + c-21];
    } else {
      int fa = f - LL;
      if      (c < 9)  v = g_prot_a[fa*9 + c];
      else if (c < 12) v = g_ptran_a[fa*3 + c-9];
      else if (c < 21) v = g_trot_a[fa*9 + c-12];
      else             v = g_ttran_a[fa*3 + c-21];
    }
    sh[i] = v;
  }
  __syncthreads();

  int p = blockIdx.x*256 + t;          // p < 6144 (grid exact)
  float px = coor[p*3],   py = coor[p*3+1],   pz = coor[p*3+2];
  float tx = target[p*3], ty = target[p*3+1], tz = target[p*3+2];
  float acc0 = 0.f, acc1 = 0.f;

  for (int q = 0; q < nf; ++q) {
    const float* fr = &sh[q*24];
    float dx = px - fr[9],  dy = py - fr[10], dz = pz - fr[11];
    float ex = tx - fr[21], ey = ty - fr[22], ez = tz - fr[23];
    float a0 = (fr[0]*dx + fr[1]*dy + fr[2]*dz) - (fr[12]*ex + fr[13]*ey + fr[14]*ez);
    float a1 = (fr[3]*dx + fr[4]*dy + fr[5]*dz) - (fr[15]*ex + fr[16]*ey + fr[17]*ez);
    float a2 = (fr[6]*dx + fr[7]*dy + fr[8]*dz) - (fr[18]*ex + fr[19]*ey + fr[20]*ez);
    float d = sqrtf(a0*a0 + a1*a1 + a2*a2 + 0.001f);
    if (f0 + q < LL) acc0 += fminf(d, 40.f);
    else             acc1 += fminf(d, 5.f);
  }

  for (int o = 32; o >= 1; o >>= 1) {
    acc0 += __shfl_down(acc0, o);
    acc1 += __shfl_down(acc1, o);
  }
  __shared__ float w0[4], w1[4];
  int lane = t & 63, wid = t >> 6;
  if (lane == 0) { w0[wid] = acc0; w1[wid] = acc1; }
  __syncthreads();
  if (t == 0) {
    double s0 = (double)w0[0] + (double)w0[1] + (double)w0[2] + (double)w0[3];
    double s1 = (double)w1[0] + (double)w1[1] + (double)w1[2] + (double)w1[3];
    if (s0 != 0.0) atomicAdd(&g_sum[0], s0);
    if (s1 != 0.0) atomicAdd(&g_sum[1], s1);
  }
}

__global__ void k_final(float* __restrict__ out) {
  int K = g_K;
  double fape = g_sum[0] / ((double)LL * (double)PP);
  double r;
  if (K == 0) {
    r = fape / 10.0;
  } else {
    double fp = g_sum[1] / ((double)(LL + K) * (double)PP);
    r = (fape + fp) / 10.0;
  }
  out[0] = (float)r;
}

extern "C" void kernel_launch(void* const* d_in, const int* in_sizes, int n_in,
                              void* d_out, int out_size, void* d_ws, size_t ws_size,
                              hipStream_t stream) {
  const float* coor   = (const float*)d_in[0];
  const float* prot   = (const float*)d_in[1];
  const float* ptran  = (const float*)d_in[2];
  const float* target = (const float*)d_in[3];
  const int*   matrix = (const int*)d_in[4];
  float* out = (float*)d_out;

  k_init<<<8, 256, 0, stream>>>();
  k_tframes<<<8, 256, 0, stream>>>(target);
  k_findpairs<<<(LL*LL)/256, 256, 0, stream>>>(matrix);
  k_scan<<<1, 1024, 0, stream>>>();
  k_build_aug<<<16, 256, 0, stream>>>(coor, target);
  k_aug_frames<<<16, 256, 0, stream>>>();
  dim3 grid(PP/256, (3*LL)/FPB);
  k_fape<<<grid, 256, 0, stream>>>(coor, prot, ptran, target);
  k_final<<<1, 1, 0, stream>>>(out);
}

// Round 2
// 63.381 us; speedup vs baseline: 1.0056x; 1.0056x over previous
//
#include <hip/hip_runtime.h>
#include <math.h>
#include <limits.h>

#define LL 2048
#define PP (LL*3)
#define FPB 64

// -------- device-global scratch (rewritten every call) --------
__device__ int   g_firstj[LL];
__device__ int   g_cnt[LL];
__device__ int   g_ii[LL];
__device__ int   g_jj[LL];
__device__ int   g_K;
__device__ float g_paug[(2*LL)*9];
__device__ float g_taug[(2*LL)*9];
// packed frame records: [A(9) | B(9) | c(3) | pad(3)] = 24 floats = 96 B
// term0: frames [0, LL); term1: frames [LL, LL + LL + K)
__device__ __align__(16) float g_frames[(3*LL)*24];
__device__ double g_sum[2];

// rigid_from_3points for one residue: x = 9 floats (x1,x2,x3 rows)
__device__ inline void rigid3(const float* x, float* rot, float* tran) {
  float x1x=x[0],x1y=x[1],x1z=x[2];
  float x2x=x[3],x2y=x[4],x2z=x[5];
  float x3x=x[6],x3y=x[7],x3z=x[8];
  float v1x=x3x-x2x, v1y=x3y-x2y, v1z=x3z-x2z;
  float v2x=x1x-x2x, v2y=x1y-x2y, v2z=x1z-x2z;
  float n1 = sqrtf(v1x*v1x+v1y*v1y+v1z*v1z) + 0.001f;
  float e1x=v1x/n1, e1y=v1y/n1, e1z=v1z/n1;
  float dd = e1x*v2x+e1y*v2y+e1z*v2z;
  float u2x=v2x-e1x*dd, u2y=v2y-e1y*dd, u2z=v2z-e1z*dd;
  float n2 = sqrtf(u2x*u2x+u2y*u2y+u2z*u2z) + 1e-8f;
  float e2x=u2x/n2, e2y=u2y/n2, e2z=u2z/n2;
  rot[0]=e1x; rot[1]=e1y; rot[2]=e1z;
  rot[3]=e2x; rot[4]=e2y; rot[5]=e2z;
  rot[6]=e1y*e2z - e1z*e2y;
  rot[7]=e1z*e2x - e1x*e2z;
  rot[8]=e1x*e2y - e1y*e2x;
  tran[0]=x2x; tran[1]=x2y; tran[2]=x2z;
}

// pack one frame record: diff = A*p - B*t - c, c = A*tp - B*tt
__device__ inline void packfr(float* fr, const float* A, const float* tp,
                              const float* B, const float* tt) {
  #pragma unroll
  for (int i = 0; i < 9; ++i) { fr[i] = A[i]; fr[9+i] = B[i]; }
  #pragma unroll
  for (int i = 0; i < 3; ++i)
    fr[18+i] = A[i*3]*tp[0] + A[i*3+1]*tp[1] + A[i*3+2]*tp[2]
             - (B[i*3]*tt[0] + B[i*3+1]*tt[1] + B[i*3+2]*tt[2]);
  fr[21] = 0.f; fr[22] = 0.f; fr[23] = 0.f;
}

// init + target frames + term0 packed records
__global__ void k_init_t0(const float* __restrict__ target,
                          const float* __restrict__ prot,
                          const float* __restrict__ ptran) {
  int f = blockIdx.x*blockDim.x + threadIdx.x;
  if (f == 0) { g_sum[0] = 0.0; g_sum[1] = 0.0; }
  if (f >= LL) return;
  g_firstj[f] = INT_MAX;
  float B[9], tt[3];
  rigid3(target + f*9, B, tt);
  float A[9], tp[3];
  #pragma unroll
  for (int i = 0; i < 9; ++i) A[i] = prot[f*9+i];
  #pragma unroll
  for (int i = 0; i < 3; ++i) tp[i] = ptran[f*3+i];
  packfr(g_frames + f*24, A, tp, B, tt);
}

// first nonzero above the diagonal per row (triu(m,1) semantics); int4 loads
__global__ void k_findpairs(const int4* __restrict__ m) {
  int idx = blockIdx.x*blockDim.x + threadIdx.x;   // one int4 each
  int4 v = m[idx];
  if ((v.x | v.y | v.z | v.w) == 0) return;
  int base = idx*4;
  int i = base >> 11;          // row (2048 divisible by 4)
  int j = base & (LL-1);
  if (v.x && (j   > i)) atomicMin(&g_firstj[i], j);
  if (v.y && (j+1 > i)) atomicMin(&g_firstj[i], j+1);
  if (v.z && (j+2 > i)) atomicMin(&g_firstj[i], j+2);
  if (v.w && (j+3 > i)) atomicMin(&g_firstj[i], j+3);
}

// single block: exclusive prefix-sum of "row has pair", build ii/jj, K
__global__ void __launch_bounds__(1024) k_scan() {
  int t = threadIdx.x;
  int r0 = 2*t, r1 = 2*t+1;
  int f0 = g_firstj[r0], f1 = g_firstj[r1];
  int h0 = (f0 != INT_MAX) ? 1 : 0;
  int h1 = (f1 != INT_MAX) ? 1 : 0;
  int local = h0 + h1;
  int lane = t & 63;
  int wid  = t >> 6;                 // 16 waves
  int incl = local;
  for (int o = 1; o < 64; o <<= 1) {
    int v = __shfl_up(incl, o);
    if (lane >= o) incl += v;
  }
  __shared__ int wsum[16];
  if (lane == 63) wsum[wid] = incl;
  __syncthreads();
  if (t < 16) {
    int iv = wsum[t];
    for (int o = 1; o < 16; o <<= 1) {
      int u = __shfl_up(iv, o);
      if (t >= o) iv += u;
    }
    wsum[t] = iv;
  }
  __syncthreads();
  int waveoff = (wid == 0) ? 0 : wsum[wid-1];
  int excl = waveoff + incl - local;   // pairs among rows < r0
  g_cnt[r0] = excl;
  g_cnt[r1] = excl + h0;
  if (h0) { g_ii[excl]      = r0; g_jj[excl]      = f0; }
  if (h1) { g_ii[excl + h0] = r1; g_jj[excl + h0] = f1; }
  if (t == 1023) g_K = waveoff + incl;
}

__global__ void k_build_aug(const float* __restrict__ coor,
                            const float* __restrict__ target) {
  int idx = blockIdx.x*blockDim.x + threadIdx.x;
  if (idx < LL) {
    int pos = idx + g_cnt[idx];
    #pragma unroll
    for (int c = 0; c < 9; ++c) {
      g_paug[pos*9+c] = coor[idx*9+c];
      g_taug[pos*9+c] = target[idx*9+c];
    }
  } else {
    int k = idx - LL;
    if (k < g_K) {
      int a = g_ii[k], b = g_jj[k];
      int pos = a + k + 1;
      #pragma unroll
      for (int c = 0; c < 9; ++c) {
        g_paug[pos*9+c] = 0.5f*(coor[a*9+c]   + coor[b*9+c]);
        g_taug[pos*9+c] = 0.5f*(target[a*9+c] + target[b*9+c]);
      }
    }
  }
}

// augmented frames -> packed records at [LL, LL+LL+K)
__global__ void k_aug_frames() {
  int n = blockIdx.x*blockDim.x + threadIdx.x;
  if (n >= LL + g_K) return;
  float A[9], tp[3], B[9], tt[3];
  rigid3(g_paug + n*9, A, tp);
  rigid3(g_taug + n*9, B, tt);
  packfr(g_frames + (size_t)(LL + n)*24, A, tp, B, tt);
}

// fused FAPE over packed frames; frame block never straddles f=LL (64|2048)
__global__ void __launch_bounds__(256) k_fape(const float* __restrict__ coor,
                                              const float* __restrict__ target) {
  int Ftot = 2*LL + g_K;
  int f0 = blockIdx.y * FPB;
  if (f0 >= Ftot) return;
  int nf = min(FPB, Ftot - f0);
  int term1 = (f0 >= LL) ? 1 : 0;
  float clampv = term1 ? 5.f : 40.f;

  int p = blockIdx.x*256 + threadIdx.x;          // p < 6144 (grid exact)
  float px = coor[p*3],   py = coor[p*3+1],   pz = coor[p*3+2];
  float tx = target[p*3], ty = target[p*3+1], tz = target[p*3+2];
  float acc = 0.f;

  const float* frb = g_frames + (size_t)f0*24;
  for (int q = 0; q < nf; ++q) {
    const float* fr = frb + q*24;
    float a0 = fr[0]*px + fr[1]*py + fr[2]*pz - fr[ 9]*tx - fr[10]*ty - fr[11]*tz - fr[18];
    float a1 = fr[3]*px + fr[4]*py + fr[5]*pz - fr[12]*tx - fr[13]*ty - fr[14]*tz - fr[19];
    float a2 = fr[6]*px + fr[7]*py + fr[8]*pz - fr[15]*tx - fr[16]*ty - fr[17]*tz - fr[20];
    float ss = a0*a0 + a1*a1 + a2*a2 + 0.001f;
    float d  = __builtin_amdgcn_sqrtf(ss);
    acc += fminf(d, clampv);
  }

  for (int o = 32; o >= 1; o >>= 1) acc += __shfl_down(acc, o);
  __shared__ float w[4];
  int lane = threadIdx.x & 63, wid = threadIdx.x >> 6;
  if (lane == 0) w[wid] = acc;
  __syncthreads();
  if (threadIdx.x == 0) {
    double s = (double)w[0] + (double)w[1] + (double)w[2] + (double)w[3];
    atomicAdd(&g_sum[term1], s);
  }
}

__global__ void k_final(float* __restrict__ out) {
  int K = g_K;
  double fape = g_sum[0] / ((double)LL * (double)PP);
  double r;
  if (K == 0) {
    r = fape / 10.0;
  } else {
    double fp = g_sum[1] / ((double)(LL + K) * (double)PP);
    r = (fape + fp) / 10.0;
  }
  out[0] = (float)r;
}

extern "C" void kernel_launch(void* const* d_in, const int* in_sizes, int n_in,
                              void* d_out, int out_size, void* d_ws, size_t ws_size,
                              hipStream_t stream) {
  const float* coor   = (const float*)d_in[0];
  const float* prot   = (const float*)d_in[1];
  const float* ptran  = (const float*)d_in[2];
  const float* target = (const float*)d_in[3];
  const int*   matrix = (const int*)d_in[4];
  float* out = (float*)d_out;

  k_init_t0<<<8, 256, 0, stream>>>(target, prot, ptran);
  k_findpairs<<<(LL*LL/4)/256, 256, 0, stream>>>((const int4*)matrix);
  k_scan<<<1, 1024, 0, stream>>>();
  k_build_aug<<<16, 256, 0, stream>>>(coor, target);
  k_aug_frames<<<16, 256, 0, stream>>>();
  dim3 grid(PP/256, (3*LL)/FPB);
  k_fape<<<grid, 256, 0, stream>>>(coor, target);
  k_final<<<1, 1, 0, stream>>>(out);
}

// Round 3
// 58.161 us; speedup vs baseline: 1.0958x; 1.0898x over previous
//
#include <hip/hip_runtime.h>
#include <math.h>
#include <limits.h>

#define LL 2048
#define PP (LL*3)
#define FPB 64

// -------- device-global scratch (rewritten every call) --------
__device__ int   g_firstj[LL];
__device__ int   g_cnt[LL];
__device__ int   g_ii[LL];
__device__ int   g_jj[LL];
__device__ int   g_K;
// packed frame records: [A(9) | B(9) | c(3) | pad(3)] = 24 floats = 96 B
// term0: frames [0, LL); term1: frames [LL, LL + LL + K)
__device__ __align__(16) float g_frames[(3*LL)*24];
__device__ double g_sum[2];

// rigid_from_3points for one residue: x = 9 floats (x1,x2,x3 rows)
__device__ inline void rigid3(const float* x, float* rot, float* tran) {
  float x1x=x[0],x1y=x[1],x1z=x[2];
  float x2x=x[3],x2y=x[4],x2z=x[5];
  float x3x=x[6],x3y=x[7],x3z=x[8];
  float v1x=x3x-x2x, v1y=x3y-x2y, v1z=x3z-x2z;
  float v2x=x1x-x2x, v2y=x1y-x2y, v2z=x1z-x2z;
  float n1 = sqrtf(v1x*v1x+v1y*v1y+v1z*v1z) + 0.001f;
  float e1x=v1x/n1, e1y=v1y/n1, e1z=v1z/n1;
  float dd = e1x*v2x+e1y*v2y+e1z*v2z;
  float u2x=v2x-e1x*dd, u2y=v2y-e1y*dd, u2z=v2z-e1z*dd;
  float n2 = sqrtf(u2x*u2x+u2y*u2y+u2z*u2z) + 1e-8f;
  float e2x=u2x/n2, e2y=u2y/n2, e2z=u2z/n2;
  rot[0]=e1x; rot[1]=e1y; rot[2]=e1z;
  rot[3]=e2x; rot[4]=e2y; rot[5]=e2z;
  rot[6]=e1y*e2z - e1z*e2y;
  rot[7]=e1z*e2x - e1x*e2z;
  rot[8]=e1x*e2y - e1y*e2x;
  tran[0]=x2x; tran[1]=x2y; tran[2]=x2z;
}

// pack one frame record: diff = A*p - B*t - c, c = A*tp - B*tt
__device__ inline void packfr(float* fr, const float* A, const float* tp,
                              const float* B, const float* tt) {
  #pragma unroll
  for (int i = 0; i < 9; ++i) { fr[i] = A[i]; fr[9+i] = B[i]; }
  #pragma unroll
  for (int i = 0; i < 3; ++i)
    fr[18+i] = A[i*3]*tp[0] + A[i*3+1]*tp[1] + A[i*3+2]*tp[2]
             - (B[i*3]*tt[0] + B[i*3+1]*tt[1] + B[i*3+2]*tt[2]);
  fr[21] = 0.f; fr[22] = 0.f; fr[23] = 0.f;
}

// blocks [0,2048): per-row scan of matrix for first j>i with m!=0 (no atomics)
// blocks [2048,2056): term0 frame packing
__global__ void __launch_bounds__(256) k_prep(const int4* __restrict__ m4,
                                              const float* __restrict__ target,
                                              const float* __restrict__ prot,
                                              const float* __restrict__ ptran) {
  int bid = blockIdx.x;
  int t = threadIdx.x;
  if (bid < LL) {
    int i = bid;                        // row
    const int4* row = m4 + (size_t)i*512;   // 2048 cols = 512 int4
    int4 a = row[2*t], b = row[2*t+1];
    int j0 = t*8;
    int best = INT_MAX;
    if (a.x && (j0   > i)) best = j0;
    if (a.y && (j0+1 > i)) best = min(best, j0+1);
    if (a.z && (j0+2 > i)) best = min(best, j0+2);
    if (a.w && (j0+3 > i)) best = min(best, j0+3);
    if (b.x && (j0+4 > i)) best = min(best, j0+4);
    if (b.y && (j0+5 > i)) best = min(best, j0+5);
    if (b.z && (j0+6 > i)) best = min(best, j0+6);
    if (b.w && (j0+7 > i)) best = min(best, j0+7);
    for (int o = 32; o >= 1; o >>= 1) best = min(best, __shfl_xor(best, o));
    __shared__ int wmin[4];
    int lane = t & 63, wid = t >> 6;
    if (lane == 0) wmin[wid] = best;
    __syncthreads();
    if (t == 0)
      g_firstj[i] = min(min(wmin[0], wmin[1]), min(wmin[2], wmin[3]));
  } else {
    int f = (bid - LL)*256 + t;
    if (f == 0) { g_sum[0] = 0.0; g_sum[1] = 0.0; }
    if (f >= LL) return;
    float B[9], tt[3];
    rigid3(target + f*9, B, tt);
    float A[9], tp[3];
    #pragma unroll
    for (int i = 0; i < 9; ++i) A[i] = prot[f*9+i];
    #pragma unroll
    for (int i = 0; i < 3; ++i) tp[i] = ptran[f*3+i];
    packfr(g_frames + f*24, A, tp, B, tt);
  }
}

// single block: exclusive prefix-sum of "row has pair", build ii/jj, K
__global__ void __launch_bounds__(1024) k_scan() {
  int t = threadIdx.x;
  int r0 = 2*t, r1 = 2*t+1;
  int f0 = g_firstj[r0], f1 = g_firstj[r1];
  int h0 = (f0 != INT_MAX) ? 1 : 0;
  int h1 = (f1 != INT_MAX) ? 1 : 0;
  int local = h0 + h1;
  int lane = t & 63;
  int wid  = t >> 6;                 // 16 waves
  int incl = local;
  for (int o = 1; o < 64; o <<= 1) {
    int v = __shfl_up(incl, o);
    if (lane >= o) incl += v;
  }
  __shared__ int wsum[16];
  if (lane == 63) wsum[wid] = incl;
  __syncthreads();
  if (t < 16) {
    int iv = wsum[t];
    for (int o = 1; o < 16; o <<= 1) {
      int u = __shfl_up(iv, o);
      if (t >= o) iv += u;
    }
    wsum[t] = iv;
  }
  __syncthreads();
  int waveoff = (wid == 0) ? 0 : wsum[wid-1];
  int excl = waveoff + incl - local;   // pairs among rows < r0
  g_cnt[r0] = excl;
  g_cnt[r1] = excl + h0;
  if (h0) { g_ii[excl]      = r0; g_jj[excl]      = f0; }
  if (h1) { g_ii[excl + h0] = r1; g_jj[excl + h0] = f1; }
  if (t == 1023) g_K = waveoff + incl;
}

// term1 packed frame records computed directly from coords (no aug buffers)
__global__ void k_augfr(const float* __restrict__ coor,
                        const float* __restrict__ target) {
  int idx = blockIdx.x*blockDim.x + threadIdx.x;
  float xp[9], xt[9];
  int pos;
  if (idx < LL) {
    pos = idx + g_cnt[idx];
    #pragma unroll
    for (int c = 0; c < 9; ++c) { xp[c] = coor[idx*9+c]; xt[c] = target[idx*9+c]; }
  } else {
    int k = idx - LL;
    if (k >= g_K) return;
    int a = g_ii[k], b = g_jj[k];
    pos = a + k + 1;
    #pragma unroll
    for (int c = 0; c < 9; ++c) {
      xp[c] = 0.5f*(coor[a*9+c]   + coor[b*9+c]);
      xt[c] = 0.5f*(target[a*9+c] + target[b*9+c]);
    }
  }
  float A[9], tp[3], B[9], tt[3];
  rigid3(xp, A, tp);
  rigid3(xt, B, tt);
  packfr(g_frames + (size_t)(LL + pos)*24, A, tp, B, tt);
}

// fused FAPE over packed frames; frame block never straddles f=LL (64|2048)
__global__ void __launch_bounds__(256) k_fape(const float* __restrict__ coor,
                                              const float* __restrict__ target) {
  __shared__ float4 sh4[FPB*6];     // 64 frames x 96 B = 6 KB
  int Ftot = 2*LL + g_K;
  int f0 = blockIdx.y * FPB;
  if (f0 >= Ftot) return;
  int nf = min(FPB, Ftot - f0);
  int term1 = (f0 >= LL) ? 1 : 0;
  float clampv = term1 ? 5.f : 40.f;
  int t = threadIdx.x;

  const float4* gfr4 = reinterpret_cast<const float4*>(g_frames) + (size_t)f0*6;
  for (int i = t; i < nf*6; i += 256) sh4[i] = gfr4[i];
  __syncthreads();

  int p = blockIdx.x*256 + t;            // p < 6144 (grid exact)
  float px = coor[p*3],   py = coor[p*3+1],   pz = coor[p*3+2];
  float ntx = -target[p*3], nty = -target[p*3+1], ntz = -target[p*3+2];
  float acc = 0.f;

  #pragma unroll 4
  for (int q = 0; q < nf; ++q) {
    float4 f0v = sh4[q*6+0];   // A0 A1 A2 A3
    float4 f1v = sh4[q*6+1];   // A4 A5 A6 A7
    float4 f2v = sh4[q*6+2];   // A8 B0 B1 B2
    float4 f3v = sh4[q*6+3];   // B3 B4 B5 B6
    float4 f4v = sh4[q*6+4];   // B7 B8 c0 c1
    float4 f5v = sh4[q*6+5];   // c2 .. .. ..
    float a0 = f0v.x*px + f0v.y*py + f0v.z*pz + f2v.y*ntx + f2v.z*nty + f2v.w*ntz - f4v.z;
    float a1 = f0v.w*px + f1v.x*py + f1v.y*pz + f3v.x*ntx + f3v.y*nty + f3v.z*ntz - f4v.w;
    float a2 = f1v.z*px + f1v.w*py + f2v.x*pz + f3v.w*ntx + f4v.x*nty + f4v.y*ntz - f5v.x;
    float ss = a0*a0 + a1*a1 + a2*a2 + 0.001f;
    float d  = __builtin_amdgcn_sqrtf(ss);
    acc += fminf(d, clampv);
  }

  for (int o = 32; o >= 1; o >>= 1) acc += __shfl_down(acc, o);
  __shared__ float w[4];
  int lane = t & 63, wid = t >> 6;
  if (lane == 0) w[wid] = acc;
  __syncthreads();
  if (t == 0) {
    double s = (double)w[0] + (double)w[1] + (double)w[2] + (double)w[3];
    atomicAdd(&g_sum[term1], s);
  }
}

__global__ void k_final(float* __restrict__ out) {
  int K = g_K;
  double fape = g_sum[0] / ((double)LL * (double)PP);
  double r;
  if (K == 0) {
    r = fape / 10.0;
  } else {
    double fp = g_sum[1] / ((double)(LL + K) * (double)PP);
    r = (fape + fp) / 10.0;
  }
  out[0] = (float)r;
}

extern "C" void kernel_launch(void* const* d_in, const int* in_sizes, int n_in,
                              void* d_out, int out_size, void* d_ws, size_t ws_size,
                              hipStream_t stream) {
  const float* coor   = (const float*)d_in[0];
  const float* prot   = (const float*)d_in[1];
  const float* ptran  = (const float*)d_in[2];
  const float* target = (const float*)d_in[3];
  const int*   matrix = (const int*)d_in[4];
  float* out = (float*)d_out;

  k_prep<<<LL + 8, 256, 0, stream>>>((const int4*)matrix, target, prot, ptran);
  k_scan<<<1, 1024, 0, stream>>>();
  k_augfr<<<16, 256, 0, stream>>>(coor, target);
  dim3 grid(PP/256, (3*LL)/FPB);
  k_fape<<<grid, 256, 0, stream>>>(coor, target);
  k_final<<<1, 1, 0, stream>>>(out);
}

// Round 4
// 45.314 us; speedup vs baseline: 1.4065x; 1.2835x over previous
//
#include <hip/hip_runtime.h>
#include <math.h>
#include <limits.h>

#define LL 2048
#define PP (LL*3)
#define FPB 32
#define NP 8

// -------- device-global scratch (rewritten every call) --------
__device__ int   g_firstj[LL];
__device__ int   g_cnt[LL];
__device__ int   g_ii[LL];
__device__ int   g_jj[LL];
__device__ int   g_K;
// packed frame records: [A(9) | B(9) | c(3) | pad(3)] = 24 floats = 96 B
// term0: frames [0, LL); term1: frames [LL, LL + LL + K)
__device__ __align__(16) float g_frames[(3*LL)*24];
__device__ double g_sum[2];

// rigid_from_3points for one residue: x = 9 floats (x1,x2,x3 rows)
__device__ inline void rigid3(const float* x, float* rot, float* tran) {
  float x1x=x[0],x1y=x[1],x1z=x[2];
  float x2x=x[3],x2y=x[4],x2z=x[5];
  float x3x=x[6],x3y=x[7],x3z=x[8];
  float v1x=x3x-x2x, v1y=x3y-x2y, v1z=x3z-x2z;
  float v2x=x1x-x2x, v2y=x1y-x2y, v2z=x1z-x2z;
  float n1 = sqrtf(v1x*v1x+v1y*v1y+v1z*v1z) + 0.001f;
  float e1x=v1x/n1, e1y=v1y/n1, e1z=v1z/n1;
  float dd = e1x*v2x+e1y*v2y+e1z*v2z;
  float u2x=v2x-e1x*dd, u2y=v2y-e1y*dd, u2z=v2z-e1z*dd;
  float n2 = sqrtf(u2x*u2x+u2y*u2y+u2z*u2z) + 1e-8f;
  float e2x=u2x/n2, e2y=u2y/n2, e2z=u2z/n2;
  rot[0]=e1x; rot[1]=e1y; rot[2]=e1z;
  rot[3]=e2x; rot[4]=e2y; rot[5]=e2z;
  rot[6]=e1y*e2z - e1z*e2y;
  rot[7]=e1z*e2x - e1x*e2z;
  rot[8]=e1x*e2y - e1y*e2x;
  tran[0]=x2x; tran[1]=x2y; tran[2]=x2z;
}

// pack one frame record: diff = A*p - B*t - c, c = A*tp - B*tt
__device__ inline void packfr(float* fr, const float* A, const float* tp,
                              const float* B, const float* tt) {
  #pragma unroll
  for (int i = 0; i < 9; ++i) { fr[i] = A[i]; fr[9+i] = B[i]; }
  #pragma unroll
  for (int i = 0; i < 3; ++i)
    fr[18+i] = A[i*3]*tp[0] + A[i*3+1]*tp[1] + A[i*3+2]*tp[2]
             - (B[i*3]*tt[0] + B[i*3+1]*tt[1] + B[i*3+2]*tt[2]);
  fr[21] = 0.f; fr[22] = 0.f; fr[23] = 0.f;
}

// blocks [0,2048): per-row scan of matrix for first j>i with m!=0 (no atomics)
// blocks [2048,2056): term0 frame packing
__global__ void __launch_bounds__(256) k_prep(const int4* __restrict__ m4,
                                              const float* __restrict__ target,
                                              const float* __restrict__ prot,
                                              const float* __restrict__ ptran) {
  int bid = blockIdx.x;
  int t = threadIdx.x;
  if (bid < LL) {
    int i = bid;                        // row
    const int4* row = m4 + (size_t)i*512;   // 2048 cols = 512 int4
    int4 a = row[2*t], b = row[2*t+1];
    int j0 = t*8;
    int best = INT_MAX;
    if (a.x && (j0   > i)) best = j0;
    if (a.y && (j0+1 > i)) best = min(best, j0+1);
    if (a.z && (j0+2 > i)) best = min(best, j0+2);
    if (a.w && (j0+3 > i)) best = min(best, j0+3);
    if (b.x && (j0+4 > i)) best = min(best, j0+4);
    if (b.y && (j0+5 > i)) best = min(best, j0+5);
    if (b.z && (j0+6 > i)) best = min(best, j0+6);
    if (b.w && (j0+7 > i)) best = min(best, j0+7);
    for (int o = 32; o >= 1; o >>= 1) best = min(best, __shfl_xor(best, o));
    __shared__ int wmin[4];
    int lane = t & 63, wid = t >> 6;
    if (lane == 0) wmin[wid] = best;
    __syncthreads();
    if (t == 0)
      g_firstj[i] = min(min(wmin[0], wmin[1]), min(wmin[2], wmin[3]));
  } else {
    int f = (bid - LL)*256 + t;
    if (f == 0) { g_sum[0] = 0.0; g_sum[1] = 0.0; }
    if (f >= LL) return;
    float B[9], tt[3];
    rigid3(target + f*9, B, tt);
    float A[9], tp[3];
    #pragma unroll
    for (int i = 0; i < 9; ++i) A[i] = prot[f*9+i];
    #pragma unroll
    for (int i = 0; i < 3; ++i) tp[i] = ptran[f*3+i];
    packfr(g_frames + f*24, A, tp, B, tt);
  }
}

// single block: exclusive prefix-sum of "row has pair", build ii/jj, K
__global__ void __launch_bounds__(1024) k_scan() {
  int t = threadIdx.x;
  int r0 = 2*t, r1 = 2*t+1;
  int f0 = g_firstj[r0], f1 = g_firstj[r1];
  int h0 = (f0 != INT_MAX) ? 1 : 0;
  int h1 = (f1 != INT_MAX) ? 1 : 0;
  int local = h0 + h1;
  int lane = t & 63;
  int wid  = t >> 6;                 // 16 waves
  int incl = local;
  for (int o = 1; o < 64; o <<= 1) {
    int v = __shfl_up(incl, o);
    if (lane >= o) incl += v;
  }
  __shared__ int wsum[16];
  if (lane == 63) wsum[wid] = incl;
  __syncthreads();
  if (t < 16) {
    int iv = wsum[t];
    for (int o = 1; o < 16; o <<= 1) {
      int u = __shfl_up(iv, o);
      if (t >= o) iv += u;
    }
    wsum[t] = iv;
  }
  __syncthreads();
  int waveoff = (wid == 0) ? 0 : wsum[wid-1];
  int excl = waveoff + incl - local;   // pairs among rows < r0
  g_cnt[r0] = excl;
  g_cnt[r1] = excl + h0;
  if (h0) { g_ii[excl]      = r0; g_jj[excl]      = f0; }
  if (h1) { g_ii[excl + h0] = r1; g_jj[excl + h0] = f1; }
  if (t == 1023) g_K = waveoff + incl;
}

// term1 packed frame records computed directly from coords (no aug buffers)
__global__ void k_augfr(const float* __restrict__ coor,
                        const float* __restrict__ target) {
  int idx = blockIdx.x*blockDim.x + threadIdx.x;
  float xp[9], xt[9];
  int pos;
  if (idx < LL) {
    pos = idx + g_cnt[idx];
    #pragma unroll
    for (int c = 0; c < 9; ++c) { xp[c] = coor[idx*9+c]; xt[c] = target[idx*9+c]; }
  } else {
    int k = idx - LL;
    if (k >= g_K) return;
    int a = g_ii[k], b = g_jj[k];
    pos = a + k + 1;
    #pragma unroll
    for (int c = 0; c < 9; ++c) {
      xp[c] = 0.5f*(coor[a*9+c]   + coor[b*9+c]);
      xt[c] = 0.5f*(target[a*9+c] + target[b*9+c]);
    }
  }
  float A[9], tp[3], B[9], tt[3];
  rigid3(xp, A, tp);
  rigid3(xt, B, tt);
  packfr(g_frames + (size_t)(LL + pos)*24, A, tp, B, tt);
}

// fused FAPE: frames (FPB/block) broadcast from LDS, NP points/thread in regs.
// FPB=32 divides LL so a block never straddles the term0/term1 boundary.
__global__ void __launch_bounds__(256) k_fape(const float* __restrict__ coor,
                                              const float* __restrict__ target) {
  __shared__ float4 sh4[FPB*6];     // 32 frames x 96 B = 3 KB
  int Ftot = 2*LL + g_K;
  int f0 = blockIdx.y * FPB;
  if (f0 >= Ftot) return;
  int nf = min(FPB, Ftot - f0);
  int term1 = (f0 >= LL) ? 1 : 0;
  float clampv = term1 ? 5.f : 40.f;
  int t = threadIdx.x;

  const float4* gfr4 = reinterpret_cast<const float4*>(g_frames) + (size_t)f0*6;
  for (int i = t; i < nf*6; i += 256) sh4[i] = gfr4[i];
  __syncthreads();

  int pbase = blockIdx.x*(256*NP) + t;   // grid.x * 256 * NP == PP exactly
  float px[NP], py[NP], pz[NP], qx[NP], qy[NP], qz[NP];
  #pragma unroll
  for (int k = 0; k < NP; ++k) {
    int p = pbase + k*256;
    px[k] = coor[p*3];    py[k] = coor[p*3+1];    pz[k] = coor[p*3+2];
    qx[k] = -target[p*3]; qy[k] = -target[p*3+1]; qz[k] = -target[p*3+2];
  }
  float acc = 0.f;

  #pragma unroll 2
  for (int q = 0; q < nf; ++q) {
    float4 v0 = sh4[q*6+0];   // A0 A1 A2 A3
    float4 v1 = sh4[q*6+1];   // A4 A5 A6 A7
    float4 v2 = sh4[q*6+2];   // A8 B0 B1 B2
    float4 v3 = sh4[q*6+3];   // B3 B4 B5 B6
    float4 v4 = sh4[q*6+4];   // B7 B8 c0 c1
    float4 v5 = sh4[q*6+5];   // c2 .. .. ..
    #pragma unroll
    for (int k = 0; k < NP; ++k) {
      float a0 = v0.x*px[k] + v0.y*py[k] + v0.z*pz[k]
               + v2.y*qx[k] + v2.z*qy[k] + v2.w*qz[k] - v4.z;
      float a1 = v0.w*px[k] + v1.x*py[k] + v1.y*pz[k]
               + v3.x*qx[k] + v3.y*qy[k] + v3.z*qz[k] - v4.w;
      float a2 = v1.z*px[k] + v1.w*py[k] + v2.x*pz[k]
               + v3.w*qx[k] + v4.x*qy[k] + v4.y*qz[k] - v5.x;
      float ss = a0*a0 + a1*a1 + a2*a2 + 0.001f;
      acc += fminf(__builtin_amdgcn_sqrtf(ss), clampv);
    }
  }

  for (int o = 32; o >= 1; o >>= 1) acc += __shfl_down(acc, o);
  __shared__ float w[4];
  int lane = t & 63, wid = t >> 6;
  if (lane == 0) w[wid] = acc;
  __syncthreads();
  if (t == 0) {
    double s = (double)w[0] + (double)w[1] + (double)w[2] + (double)w[3];
    atomicAdd(&g_sum[term1], s);
  }
}

__global__ void k_final(float* __restrict__ out) {
  int K = g_K;
  double fape = g_sum[0] / ((double)LL * (double)PP);
  double r;
  if (K == 0) {
    r = fape / 10.0;
  } else {
    double fp = g_sum[1] / ((double)(LL + K) * (double)PP);
    r = (fape + fp) / 10.0;
  }
  out[0] = (float)r;
}

extern "C" void kernel_launch(void* const* d_in, const int* in_sizes, int n_in,
                              void* d_out, int out_size, void* d_ws, size_t ws_size,
                              hipStream_t stream) {
  const float* coor   = (const float*)d_in[0];
  const float* prot   = (const float*)d_in[1];
  const float* ptran  = (const float*)d_in[2];
  const float* target = (const float*)d_in[3];
  const int*   matrix = (const int*)d_in[4];
  float* out = (float*)d_out;

  k_prep<<<LL + 8, 256, 0, stream>>>((const int4*)matrix, target, prot, ptran);
  k_scan<<<1, 1024, 0, stream>>>();
  k_augfr<<<16, 256, 0, stream>>>(coor, target);
  dim3 grid(PP/(256*NP), (3*LL)/FPB);   // 3 x 192
  k_fape<<<grid, 256, 0, stream>>>(coor, target);
  k_final<<<1, 1, 0, stream>>>(out);
}